// Round 4
// baseline (335.834 us; speedup 1.0000x reference)
//
#include <hip/hip_runtime.h>
#include <hip/hip_bf16.h>
#include <math.h>

typedef __bf16 bf16;
typedef bf16 bf16x8 __attribute__((ext_vector_type(8)));
typedef float f32x4 __attribute__((ext_vector_type(4)));
typedef unsigned short ushort_t;
typedef unsigned long long u64;

#define N_NODES 100000
#define N_EDGES 640000
#define DD 128
#define MAXDEG 64
#define STAT_SCALE 1048576.0   // 2^20 fixed-point for deterministic stats

// tanh-form gelu; |err| <~ 1e-3, bf16 storage error dominates
__device__ __forceinline__ float gelu_fast(float x) {
    float z2 = x * (1.595769122f + 0.071354816f * x * x);
    return x * __builtin_amdgcn_rcpf(1.0f + __expf(-z2));
}

__device__ __forceinline__ ushort_t bf16_bits(float x) {
    bf16 h = (bf16)x;
    return __builtin_bit_cast(ushort_t, h);
}

__device__ __forceinline__ float bits_to_f(ushort_t u) {
    return __uint_as_float(((unsigned)u) << 16);
}

__device__ __forceinline__ long long to_fixed(double x) {
    return (long long)(x * STAT_SCALE + (x >= 0.0 ? 0.5 : -0.5));
}

// block-reduce (lsum, lsq) -> two deterministic i64 atomics
__device__ __forceinline__ void stats_atomic(float lsum, float lsq, float* red,
                                             u64* dsum, u64* dsq) {
    int tid = threadIdx.x;
    red[tid] = lsum; __syncthreads();
    for (int s = 128; s > 0; s >>= 1) { if (tid < s) red[tid] += red[tid + s]; __syncthreads(); }
    float bs = red[0]; __syncthreads();
    red[tid] = lsq; __syncthreads();
    for (int s = 128; s > 0; s >>= 1) { if (tid < s) red[tid] += red[tid + s]; __syncthreads(); }
    if (tid == 0) {
        atomicAdd(dsum, (u64)to_fixed((double)bs));
        atomicAdd(dsq,  (u64)to_fixed((double)red[0]));
    }
}

__device__ __forceinline__ void stats_decode(const u64* stats, double cnt,
                                             float* mu, float* rs) {
    long long ss = (long long)stats[0], sq = (long long)stats[1];
    double mu_d = ((double)ss / STAT_SCALE) / cnt;
    double var  = ((double)sq / STAT_SCALE) / cnt - mu_d * mu_d;
    *mu = (float)mu_d;
    *rs = (float)(1.0 / sqrt(var + 1e-5));
}

// ---------------- K1: hpre = bf16(nf @ W1 + b1) + stats ----------------------
// Operand-swapped MFMA: lane holds row=l15, cols=(l4*4..l4*4+3) -> uint2 stores.
#define K1_TILES 1563
__global__ __launch_bounds__(256) void k1_gemm1(
    const float* __restrict__ nf, const float* __restrict__ W1,
    const float* __restrict__ b1, ushort_t* __restrict__ hpre,
    u64* __restrict__ stats, int nblocks)
{
    __shared__ bf16 Ash[64 * 136];
    __shared__ float red[256];
    const int tid = threadIdx.x;
    const int lane = tid & 63;
    const int w = tid >> 6;
    const int l15 = lane & 15, l4 = lane >> 4;

    bf16x8 bfrag[4][2];
    #pragma unroll
    for (int s = 0; s < 4; ++s)
        #pragma unroll
        for (int t = 0; t < 2; ++t) {
            int n = w * 32 + t * 16 + l15;
            #pragma unroll
            for (int j = 0; j < 8; ++j)
                bfrag[s][t][j] = (bf16)W1[(s * 32 + l4 * 8 + j) * DD + n];
        }
    float4 bias4[2];
    bias4[0] = *(const float4*)&b1[w * 32 + l4 * 4];
    bias4[1] = *(const float4*)&b1[w * 32 + 16 + l4 * 4];

    float lsum = 0.f, lsq = 0.f;
    const int srow = tid >> 2;
    const int q = tid & 3;

    for (int tile = blockIdx.x; tile < K1_TILES; tile += nblocks) {
        const int rbase = tile * 64;
        {
            int grow = min(rbase + srow, N_NODES - 1);
            const float4* p = (const float4*)&nf[(size_t)grow * DD + q * 32];
            #pragma unroll
            for (int u = 0; u < 4; ++u) {
                float4 a = p[2 * u], b = p[2 * u + 1];
                ushort_t o[8] = {bf16_bits(a.x), bf16_bits(a.y), bf16_bits(a.z), bf16_bits(a.w),
                                 bf16_bits(b.x), bf16_bits(b.y), bf16_bits(b.z), bf16_bits(b.w)};
                *(uint4*)&Ash[srow * 136 + q * 32 + u * 8] = *(const uint4*)o;
            }
        }
        __syncthreads();
        f32x4 acc[4][2];
        #pragma unroll
        for (int r = 0; r < 4; ++r)
            #pragma unroll
            for (int t = 0; t < 2; ++t)
                acc[r][t] = (f32x4){0.f, 0.f, 0.f, 0.f};
        #pragma unroll
        for (int s = 0; s < 4; ++s)
            #pragma unroll
            for (int r = 0; r < 4; ++r) {
                bf16x8 a = *(const bf16x8*)&Ash[(r * 16 + l15) * 136 + s * 32 + l4 * 8];
                acc[r][0] = __builtin_amdgcn_mfma_f32_16x16x32_bf16(bfrag[s][0], a, acc[r][0], 0, 0, 0);
                acc[r][1] = __builtin_amdgcn_mfma_f32_16x16x32_bf16(bfrag[s][1], a, acc[r][1], 0, 0, 0);
            }
        __syncthreads();
        #pragma unroll
        for (int r = 0; r < 4; ++r) {
            int row = rbase + r * 16 + l15;
            if (row < N_NODES) {
                #pragma unroll
                for (int t = 0; t < 2; ++t) {
                    int col = w * 32 + t * 16 + l4 * 4;
                    ushort_t o[4];
                    #pragma unroll
                    for (int j = 0; j < 4; ++j) {
                        float v = acc[r][t][j] + bias4[t][j];
                        lsum += v; lsq += v * v;
                        o[j] = bf16_bits(v);
                    }
                    *(uint2*)&hpre[(size_t)row * DD + col] = *(const uint2*)o;
                }
            }
        }
    }
    stats_atomic(lsum, lsq, red, &stats[0], &stats[1]);
}

// ---------------- K3: hg = bf16(gelu((hpre-mu)*rs)) --------------------------
__global__ __launch_bounds__(256) void k3_act(
    const ushort_t* __restrict__ hpre, const u64* __restrict__ stats,
    ushort_t* __restrict__ hg)
{
    float mu, rs;
    stats_decode(stats, (double)N_NODES * DD, &mu, &rs);
    size_t i = (size_t)(blockIdx.x * 256 + threadIdx.x) * 8;
    uint4 v = *(const uint4*)(hpre + i);
    const ushort_t* in = (const ushort_t*)&v;
    ushort_t o[8];
    #pragma unroll
    for (int j = 0; j < 8; ++j)
        o[j] = bf16_bits(gelu_fast((bits_to_f(in[j]) - mu) * rs));
    *(uint4*)(hg + i) = *(const uint4*)o;
}

// ---------------- K4: e0 = [ef | hg[src]] @ W2 + b2 (bf16) + stats -----------
__global__ __launch_bounds__(256) void k4_gemm2(
    const float* __restrict__ ef, const ushort_t* __restrict__ hg,
    const int* __restrict__ eidx, const float* __restrict__ W2,
    const float* __restrict__ b2, ushort_t* __restrict__ e0,
    u64* __restrict__ stats, int nblocks)
{
    __shared__ bf16 Ash[64 * 264];
    __shared__ float red[256];
    const int tid = threadIdx.x;
    const int lane = tid & 63;
    const int w = tid >> 6;
    const int l15 = lane & 15, l4 = lane >> 4;

    bf16x8 bfrag[8][2];
    #pragma unroll
    for (int s = 0; s < 8; ++s)
        #pragma unroll
        for (int t = 0; t < 2; ++t) {
            int n = w * 32 + t * 16 + l15;
            #pragma unroll
            for (int j = 0; j < 8; ++j)
                bfrag[s][t][j] = (bf16)W2[(s * 32 + l4 * 8 + j) * DD + n];
        }
    float4 bias4[2];
    bias4[0] = *(const float4*)&b2[w * 32 + l4 * 4];
    bias4[1] = *(const float4*)&b2[w * 32 + 16 + l4 * 4];

    float lsum = 0.f, lsq = 0.f;
    const int srow = tid >> 2;
    const int q = tid & 3;

    for (int tile = blockIdx.x; tile < N_EDGES / 64; tile += nblocks) {
        const int ebase = tile * 64;
        {
            const float4* p = (const float4*)&ef[(size_t)(ebase + srow) * DD + q * 32];
            #pragma unroll
            for (int u = 0; u < 4; ++u) {
                float4 a = p[2 * u], b = p[2 * u + 1];
                ushort_t o[8] = {bf16_bits(a.x), bf16_bits(a.y), bf16_bits(a.z), bf16_bits(a.w),
                                 bf16_bits(b.x), bf16_bits(b.y), bf16_bits(b.z), bf16_bits(b.w)};
                *(uint4*)&Ash[srow * 264 + q * 32 + u * 8] = *(const uint4*)o;
            }
            int src = eidx[(size_t)(ebase + srow) * 2];
            const uint4* hp = (const uint4*)&hg[(size_t)src * DD + q * 32];
            uint4* hd = (uint4*)&Ash[srow * 264 + 128 + q * 32];
            #pragma unroll
            for (int u = 0; u < 4; ++u) hd[u] = hp[u];
        }
        __syncthreads();
        f32x4 acc[4][2];
        #pragma unroll
        for (int r = 0; r < 4; ++r)
            #pragma unroll
            for (int t = 0; t < 2; ++t)
                acc[r][t] = (f32x4){0.f, 0.f, 0.f, 0.f};
        #pragma unroll
        for (int s = 0; s < 8; ++s)
            #pragma unroll
            for (int r = 0; r < 4; ++r) {
                bf16x8 a = *(const bf16x8*)&Ash[(r * 16 + l15) * 264 + s * 32 + l4 * 8];
                acc[r][0] = __builtin_amdgcn_mfma_f32_16x16x32_bf16(bfrag[s][0], a, acc[r][0], 0, 0, 0);
                acc[r][1] = __builtin_amdgcn_mfma_f32_16x16x32_bf16(bfrag[s][1], a, acc[r][1], 0, 0, 0);
            }
        __syncthreads();
        #pragma unroll
        for (int r = 0; r < 4; ++r) {
            int row = ebase + r * 16 + l15;
            #pragma unroll
            for (int t = 0; t < 2; ++t) {
                int col = w * 32 + t * 16 + l4 * 4;
                ushort_t o[4];
                #pragma unroll
                for (int j = 0; j < 4; ++j) {
                    float v = acc[r][t][j] + bias4[t][j];
                    lsum += v; lsq += v * v;
                    o[j] = bf16_bits(v);
                }
                *(uint2*)&e0[(size_t)row * DD + col] = *(const uint2*)o;
            }
        }
    }
    stats_atomic(lsum, lsq, red, &stats[2], &stats[3]);
}

// ---------------- K7: bucket edges by dst ------------------------------------
__global__ __launch_bounds__(256) void k7_fill(
    const int* __restrict__ eidx, int* __restrict__ cnt, int* __restrict__ slot)
{
    int e = blockIdx.x * 256 + threadIdx.x;
    if (e >= N_EDGES) return;
    int dst = eidx[(size_t)e * 2 + 1];
    int pos = atomicAdd(&cnt[dst], 1);
    if (pos < MAXDEG) slot[dst * MAXDEG + pos] = e;
}

// ---------------- K8: per-node gather + norm + fast-gelu + mean --------------
__global__ __launch_bounds__(256) void k8_gather(
    const ushort_t* __restrict__ e0v, const int* __restrict__ slot,
    const int* __restrict__ cnt, const u64* __restrict__ stats,
    float* __restrict__ out)
{
    float mu, rs;
    stats_decode(stats + 2, (double)N_EDGES * DD, &mu, &rs);
    int node = (int)((blockIdx.x * 256 + threadIdx.x) >> 6);
    int lane = threadIdx.x & 63;
    if (node >= N_NODES) return;
    int c = cnt[node];
    int m = min(c, MAXDEG);
    int myslot = (lane < m) ? slot[node * MAXDEG + lane] : 0;
    float a0 = 0.f, a1 = 0.f;
    const size_t off = (size_t)(lane * 2);
    int j = 0;
    for (; j + 4 <= m; j += 4) {
        int ea = __shfl(myslot, j);
        int eb = __shfl(myslot, j + 1);
        int ec = __shfl(myslot, j + 2);
        int ed = __shfl(myslot, j + 3);
        unsigned ua = *(const unsigned*)&e0v[(size_t)ea * DD + off];
        unsigned ub = *(const unsigned*)&e0v[(size_t)eb * DD + off];
        unsigned uc = *(const unsigned*)&e0v[(size_t)ec * DD + off];
        unsigned ud = *(const unsigned*)&e0v[(size_t)ed * DD + off];
        a0 += gelu_fast((__uint_as_float(ua << 16) - mu) * rs);
        a1 += gelu_fast((__uint_as_float(ua & 0xffff0000u) - mu) * rs);
        a0 += gelu_fast((__uint_as_float(ub << 16) - mu) * rs);
        a1 += gelu_fast((__uint_as_float(ub & 0xffff0000u) - mu) * rs);
        a0 += gelu_fast((__uint_as_float(uc << 16) - mu) * rs);
        a1 += gelu_fast((__uint_as_float(uc & 0xffff0000u) - mu) * rs);
        a0 += gelu_fast((__uint_as_float(ud << 16) - mu) * rs);
        a1 += gelu_fast((__uint_as_float(ud & 0xffff0000u) - mu) * rs);
    }
    for (; j < m; ++j) {
        int ea = __shfl(myslot, j);
        unsigned ua = *(const unsigned*)&e0v[(size_t)ea * DD + off];
        a0 += gelu_fast((__uint_as_float(ua << 16) - mu) * rs);
        a1 += gelu_fast((__uint_as_float(ua & 0xffff0000u) - mu) * rs);
    }
    float inv = c > 0 ? 1.0f / (float)c : 0.f;
    float2 res = {a0 * inv, a1 * inv};
    *(float2*)&out[(size_t)node * DD + lane * 2] = res;
}

// ---------------- launch -----------------------------------------------------
extern "C" void kernel_launch(void* const* d_in, const int* in_sizes, int n_in,
                              void* d_out, int out_size, void* d_ws, size_t ws_size,
                              hipStream_t stream) {
    const float* ef  = (const float*)d_in[0];
    const float* nf  = (const float*)d_in[1];
    const int*   eix = (const int*)d_in[2];
    const float* W1  = (const float*)d_in[3];
    const float* b1  = (const float*)d_in[4];
    const float* W2  = (const float*)d_in[5];
    const float* b2  = (const float*)d_in[6];
    float* out = (float*)d_out;
    char* ws = (char*)d_ws;

    ushort_t* hpre  = (ushort_t*)(ws + 0);           // 25,600,000
    ushort_t* hg    = (ushort_t*)(ws + 25600000);    // 25,600,000
    ushort_t* e0    = (ushort_t*)(ws + 51200000);    // 163,840,000
    int*      cnt   = (int*)(ws + 215040000);        // 400,000
    u64*      stats = (u64*)(ws + 215440000);        // 32 B (s1 sum/sq, s2 sum/sq)
    int*      slot  = (int*)(ws + 215440064);        // 25,600,000

    // zero cnt + stats every call (atomics accumulate; ws not re-poisoned)
    hipMemsetAsync(cnt, 0, 400000 + 64, stream);
    k1_gemm1<<<521, 256, 0, stream>>>(nf, W1, b1, hpre, stats, 521);
    k3_act<<<6250, 256, 0, stream>>>(hpre, stats, hg);
    k7_fill<<<2500, 256, 0, stream>>>(eix, cnt, slot);
    k4_gemm2<<<2500, 256, 0, stream>>>(ef, hg, eix, W2, b2, e0, stats, 2500);
    k8_gather<<<25000, 256, 0, stream>>>(e0, slot, cnt, stats, out);
}

// Round 5
// 311.323 us; speedup vs baseline: 1.0787x; 1.0787x over previous
//
#include <hip/hip_runtime.h>
#include <hip/hip_bf16.h>
#include <math.h>

typedef __bf16 bf16;
typedef bf16 bf16x8 __attribute__((ext_vector_type(8)));
typedef float f32x4 __attribute__((ext_vector_type(4)));
typedef unsigned short ushort_t;
typedef unsigned long long u64;

#define N_NODES 100000
#define N_EDGES 640000
#define DD 128
#define MAXDEG 64
#define STAT_SCALE 1048576.0

__device__ __forceinline__ float gelu_fast(float x) {
    float z2 = x * (1.595769122f + 0.071354816f * x * x);
    return x * __builtin_amdgcn_rcpf(1.0f + __expf(-z2));
}

__device__ __forceinline__ ushort_t bf16_bits(float x) {
    bf16 h = (bf16)x;
    return __builtin_bit_cast(ushort_t, h);
}

__device__ __forceinline__ float bits_to_f(ushort_t u) {
    return __uint_as_float(((unsigned)u) << 16);
}

__device__ __forceinline__ long long to_fixed(double x) {
    return (long long)(x * STAT_SCALE + (x >= 0.0 ? 0.5 : -0.5));
}

__device__ __forceinline__ void stats_atomic(float lsum, float lsq, float* red,
                                             u64* dsum, u64* dsq) {
    int tid = threadIdx.x;
    red[tid] = lsum; __syncthreads();
    for (int s = 128; s > 0; s >>= 1) { if (tid < s) red[tid] += red[tid + s]; __syncthreads(); }
    float bs = red[0]; __syncthreads();
    red[tid] = lsq; __syncthreads();
    for (int s = 128; s > 0; s >>= 1) { if (tid < s) red[tid] += red[tid + s]; __syncthreads(); }
    if (tid == 0) {
        atomicAdd(dsum, (u64)to_fixed((double)bs));
        atomicAdd(dsq,  (u64)to_fixed((double)red[0]));
    }
}

__device__ __forceinline__ void stats_decode(const u64* stats, double cnt,
                                             float* mu, float* rs) {
    long long ss = (long long)stats[0], sq = (long long)stats[1];
    double mu_d = ((double)ss / STAT_SCALE) / cnt;
    double var  = ((double)sq / STAT_SCALE) / cnt - mu_d * mu_d;
    *mu = (float)mu_d;
    *rs = (float)(1.0 / sqrt(var + 1e-5));
}

// ---------------- K1: hpre = bf16(nf @ W1 + b1) + stats1 ---------------------
#define K1_TILES 1563
__global__ __launch_bounds__(256) void k1_gemm1(
    const float* __restrict__ nf, const float* __restrict__ W1,
    const float* __restrict__ b1, ushort_t* __restrict__ hpre,
    u64* __restrict__ stats, int nblocks)
{
    __shared__ bf16 Ash[64 * 136];
    __shared__ float red[256];
    const int tid = threadIdx.x;
    const int lane = tid & 63;
    const int w = tid >> 6;
    const int l15 = lane & 15, l4 = lane >> 4;

    bf16x8 bfrag[4][2];
    #pragma unroll
    for (int s = 0; s < 4; ++s)
        #pragma unroll
        for (int t = 0; t < 2; ++t) {
            int n = w * 32 + t * 16 + l15;
            #pragma unroll
            for (int j = 0; j < 8; ++j)
                bfrag[s][t][j] = (bf16)W1[(s * 32 + l4 * 8 + j) * DD + n];
        }
    float4 bias4[2];
    bias4[0] = *(const float4*)&b1[w * 32 + l4 * 4];
    bias4[1] = *(const float4*)&b1[w * 32 + 16 + l4 * 4];

    float lsum = 0.f, lsq = 0.f;
    const int srow = tid >> 2;
    const int q = tid & 3;

    for (int tile = blockIdx.x; tile < K1_TILES; tile += nblocks) {
        const int rbase = tile * 64;
        {
            int grow = min(rbase + srow, N_NODES - 1);
            const float4* p = (const float4*)&nf[(size_t)grow * DD + q * 32];
            #pragma unroll
            for (int u = 0; u < 4; ++u) {
                float4 a = p[2 * u], b = p[2 * u + 1];
                ushort_t o[8] = {bf16_bits(a.x), bf16_bits(a.y), bf16_bits(a.z), bf16_bits(a.w),
                                 bf16_bits(b.x), bf16_bits(b.y), bf16_bits(b.z), bf16_bits(b.w)};
                *(uint4*)&Ash[srow * 136 + q * 32 + u * 8] = *(const uint4*)o;
            }
        }
        __syncthreads();
        f32x4 acc[4][2];
        #pragma unroll
        for (int r = 0; r < 4; ++r)
            #pragma unroll
            for (int t = 0; t < 2; ++t)
                acc[r][t] = (f32x4){0.f, 0.f, 0.f, 0.f};
        #pragma unroll
        for (int s = 0; s < 4; ++s)
            #pragma unroll
            for (int r = 0; r < 4; ++r) {
                bf16x8 a = *(const bf16x8*)&Ash[(r * 16 + l15) * 136 + s * 32 + l4 * 8];
                acc[r][0] = __builtin_amdgcn_mfma_f32_16x16x32_bf16(bfrag[s][0], a, acc[r][0], 0, 0, 0);
                acc[r][1] = __builtin_amdgcn_mfma_f32_16x16x32_bf16(bfrag[s][1], a, acc[r][1], 0, 0, 0);
            }
        __syncthreads();
        #pragma unroll
        for (int r = 0; r < 4; ++r) {
            int row = rbase + r * 16 + l15;
            if (row < N_NODES) {
                #pragma unroll
                for (int t = 0; t < 2; ++t) {
                    int col = w * 32 + t * 16 + l4 * 4;
                    ushort_t o[4];
                    #pragma unroll
                    for (int j = 0; j < 4; ++j) {
                        float v = acc[r][t][j] + bias4[t][j];
                        lsum += v; lsq += v * v;
                        o[j] = bf16_bits(v);
                    }
                    *(uint2*)&hpre[(size_t)row * DD + col] = *(const uint2*)o;
                }
            }
        }
    }
    stats_atomic(lsum, lsq, red, &stats[0], &stats[1]);
}

// ---------------- K2b: hh = bf16( gelu(LN(hpre)) @ W2_bot ) ------------------
// norm+gelu fused into the staging convert; no separate K3 pass.
__global__ __launch_bounds__(256) void k2b_gemmh(
    const ushort_t* __restrict__ hpre, const float* __restrict__ W2,
    const u64* __restrict__ stats, ushort_t* __restrict__ hh, int nblocks)
{
    __shared__ bf16 Ash[64 * 136];
    float mu, rs;
    stats_decode(stats, (double)N_NODES * DD, &mu, &rs);

    const int tid = threadIdx.x;
    const int lane = tid & 63;
    const int w = tid >> 6;
    const int l15 = lane & 15, l4 = lane >> 4;

    bf16x8 bfrag[4][2];
    #pragma unroll
    for (int s = 0; s < 4; ++s)
        #pragma unroll
        for (int t = 0; t < 2; ++t) {
            int n = w * 32 + t * 16 + l15;
            #pragma unroll
            for (int j = 0; j < 8; ++j)
                bfrag[s][t][j] = (bf16)W2[(DD + s * 32 + l4 * 8 + j) * DD + n];  // bottom half
        }

    const int srow = tid >> 2;
    const int q = tid & 3;

    for (int tile = blockIdx.x; tile < K1_TILES; tile += nblocks) {
        const int rbase = tile * 64;
        {
            int grow = min(rbase + srow, N_NODES - 1);
            const uint4* p = (const uint4*)&hpre[(size_t)grow * DD + q * 32];
            #pragma unroll
            for (int u = 0; u < 4; ++u) {
                uint4 v = p[u];
                const ushort_t* in = (const ushort_t*)&v;
                ushort_t o[8];
                #pragma unroll
                for (int j = 0; j < 8; ++j)
                    o[j] = bf16_bits(gelu_fast((bits_to_f(in[j]) - mu) * rs));
                *(uint4*)&Ash[srow * 136 + q * 32 + u * 8] = *(const uint4*)o;
            }
        }
        __syncthreads();
        f32x4 acc[4][2];
        #pragma unroll
        for (int r = 0; r < 4; ++r)
            #pragma unroll
            for (int t = 0; t < 2; ++t)
                acc[r][t] = (f32x4){0.f, 0.f, 0.f, 0.f};
        #pragma unroll
        for (int s = 0; s < 4; ++s)
            #pragma unroll
            for (int r = 0; r < 4; ++r) {
                bf16x8 a = *(const bf16x8*)&Ash[(r * 16 + l15) * 136 + s * 32 + l4 * 8];
                acc[r][0] = __builtin_amdgcn_mfma_f32_16x16x32_bf16(bfrag[s][0], a, acc[r][0], 0, 0, 0);
                acc[r][1] = __builtin_amdgcn_mfma_f32_16x16x32_bf16(bfrag[s][1], a, acc[r][1], 0, 0, 0);
            }
        __syncthreads();
        #pragma unroll
        for (int r = 0; r < 4; ++r) {
            int row = rbase + r * 16 + l15;
            if (row < N_NODES) {
                #pragma unroll
                for (int t = 0; t < 2; ++t) {
                    int col = w * 32 + t * 16 + l4 * 4;
                    ushort_t o[4];
                    #pragma unroll
                    for (int j = 0; j < 4; ++j)
                        o[j] = bf16_bits(acc[r][t][j]);
                    *(uint2*)&hh[(size_t)row * DD + col] = *(const uint2*)o;
                }
            }
        }
    }
}

// ---------------- K4: e0 = bf16( ef @ W2_top + hh[src] + b2 ) + stats2 -------
// Dense streaming GEMM; gather moved to 8B/lane epilogue adds (hh L3-resident).
__global__ __launch_bounds__(256) void k4_gemm2(
    const float* __restrict__ ef, const ushort_t* __restrict__ hh,
    const int* __restrict__ eidx, const float* __restrict__ W2,
    const float* __restrict__ b2, ushort_t* __restrict__ e0,
    u64* __restrict__ stats, int nblocks)
{
    __shared__ bf16 Ash[64 * 136];
    __shared__ int Ssrc[64];
    __shared__ float red[256];
    const int tid = threadIdx.x;
    const int lane = tid & 63;
    const int w = tid >> 6;
    const int l15 = lane & 15, l4 = lane >> 4;

    bf16x8 bfrag[4][2];
    #pragma unroll
    for (int s = 0; s < 4; ++s)
        #pragma unroll
        for (int t = 0; t < 2; ++t) {
            int n = w * 32 + t * 16 + l15;
            #pragma unroll
            for (int j = 0; j < 8; ++j)
                bfrag[s][t][j] = (bf16)W2[(s * 32 + l4 * 8 + j) * DD + n];      // top half
        }
    float4 bias4[2];
    bias4[0] = *(const float4*)&b2[w * 32 + l4 * 4];
    bias4[1] = *(const float4*)&b2[w * 32 + 16 + l4 * 4];

    float lsum = 0.f, lsq = 0.f;
    const int srow = tid >> 2;
    const int q = tid & 3;

    for (int tile = blockIdx.x; tile < N_EDGES / 64; tile += nblocks) {
        const int ebase = tile * 64;
        {
            const float4* p = (const float4*)&ef[(size_t)(ebase + srow) * DD + q * 32];
            #pragma unroll
            for (int u = 0; u < 4; ++u) {
                float4 a = p[2 * u], b = p[2 * u + 1];
                ushort_t o[8] = {bf16_bits(a.x), bf16_bits(a.y), bf16_bits(a.z), bf16_bits(a.w),
                                 bf16_bits(b.x), bf16_bits(b.y), bf16_bits(b.z), bf16_bits(b.w)};
                *(uint4*)&Ash[srow * 136 + q * 32 + u * 8] = *(const uint4*)o;
            }
            if (tid < 64) Ssrc[tid] = eidx[(size_t)(ebase + tid) * 2];
        }
        __syncthreads();
        f32x4 acc[4][2];
        #pragma unroll
        for (int r = 0; r < 4; ++r)
            #pragma unroll
            for (int t = 0; t < 2; ++t)
                acc[r][t] = (f32x4){0.f, 0.f, 0.f, 0.f};
        #pragma unroll
        for (int s = 0; s < 4; ++s)
            #pragma unroll
            for (int r = 0; r < 4; ++r) {
                bf16x8 a = *(const bf16x8*)&Ash[(r * 16 + l15) * 136 + s * 32 + l4 * 8];
                acc[r][0] = __builtin_amdgcn_mfma_f32_16x16x32_bf16(bfrag[s][0], a, acc[r][0], 0, 0, 0);
                acc[r][1] = __builtin_amdgcn_mfma_f32_16x16x32_bf16(bfrag[s][1], a, acc[r][1], 0, 0, 0);
            }
        // read src rows into registers while still inside barrier-protected region
        int srows[4];
        #pragma unroll
        for (int r = 0; r < 4; ++r) srows[r] = Ssrc[r * 16 + l15];
        __syncthreads();
        #pragma unroll
        for (int r = 0; r < 4; ++r) {
            int row = ebase + r * 16 + l15;
            #pragma unroll
            for (int t = 0; t < 2; ++t) {
                int col = w * 32 + t * 16 + l4 * 4;
                uint2 hv = *(const uint2*)&hh[(size_t)srows[r] * DD + col];
                float h0 = bits_to_f((ushort_t)(hv.x & 0xffff));
                float h1 = bits_to_f((ushort_t)(hv.x >> 16));
                float h2 = bits_to_f((ushort_t)(hv.y & 0xffff));
                float h3 = bits_to_f((ushort_t)(hv.y >> 16));
                float hadd[4] = {h0, h1, h2, h3};
                ushort_t o[4];
                #pragma unroll
                for (int j = 0; j < 4; ++j) {
                    float v = acc[r][t][j] + bias4[t][j] + hadd[j];
                    lsum += v; lsq += v * v;
                    o[j] = bf16_bits(v);
                }
                *(uint2*)&e0[(size_t)row * DD + col] = *(const uint2*)o;
            }
        }
    }
    stats_atomic(lsum, lsq, red, &stats[2], &stats[3]);
}

// ---------------- K7: bucket edges by dst ------------------------------------
__global__ __launch_bounds__(256) void k7_fill(
    const int* __restrict__ eidx, int* __restrict__ cnt, int* __restrict__ slot)
{
    int e = blockIdx.x * 256 + threadIdx.x;
    if (e >= N_EDGES) return;
    int dst = eidx[(size_t)e * 2 + 1];
    int pos = atomicAdd(&cnt[dst], 1);
    if (pos < MAXDEG) slot[dst * MAXDEG + pos] = e;
}

// ---------------- K8: per-node gather + norm + fast-gelu + mean --------------
__global__ __launch_bounds__(256) void k8_gather(
    const ushort_t* __restrict__ e0v, const int* __restrict__ slot,
    const int* __restrict__ cnt, const u64* __restrict__ stats,
    float* __restrict__ out)
{
    float mu, rs;
    stats_decode(stats + 2, (double)N_EDGES * DD, &mu, &rs);
    int node = (int)((blockIdx.x * 256 + threadIdx.x) >> 6);
    int lane = threadIdx.x & 63;
    if (node >= N_NODES) return;
    int c = cnt[node];
    int m = min(c, MAXDEG);
    int myslot = (lane < m) ? slot[node * MAXDEG + lane] : 0;
    float a0 = 0.f, a1 = 0.f;
    const size_t off = (size_t)(lane * 2);
    int j = 0;
    for (; j + 4 <= m; j += 4) {
        int ea = __shfl(myslot, j);
        int eb = __shfl(myslot, j + 1);
        int ec = __shfl(myslot, j + 2);
        int ed = __shfl(myslot, j + 3);
        unsigned ua = *(const unsigned*)&e0v[(size_t)ea * DD + off];
        unsigned ub = *(const unsigned*)&e0v[(size_t)eb * DD + off];
        unsigned uc = *(const unsigned*)&e0v[(size_t)ec * DD + off];
        unsigned ud = *(const unsigned*)&e0v[(size_t)ed * DD + off];
        a0 += gelu_fast((__uint_as_float(ua << 16) - mu) * rs);
        a1 += gelu_fast((__uint_as_float(ua & 0xffff0000u) - mu) * rs);
        a0 += gelu_fast((__uint_as_float(ub << 16) - mu) * rs);
        a1 += gelu_fast((__uint_as_float(ub & 0xffff0000u) - mu) * rs);
        a0 += gelu_fast((__uint_as_float(uc << 16) - mu) * rs);
        a1 += gelu_fast((__uint_as_float(uc & 0xffff0000u) - mu) * rs);
        a0 += gelu_fast((__uint_as_float(ud << 16) - mu) * rs);
        a1 += gelu_fast((__uint_as_float(ud & 0xffff0000u) - mu) * rs);
    }
    for (; j < m; ++j) {
        int ea = __shfl(myslot, j);
        unsigned ua = *(const unsigned*)&e0v[(size_t)ea * DD + off];
        a0 += gelu_fast((__uint_as_float(ua << 16) - mu) * rs);
        a1 += gelu_fast((__uint_as_float(ua & 0xffff0000u) - mu) * rs);
    }
    float inv = c > 0 ? 1.0f / (float)c : 0.f;
    float2 res = {a0 * inv, a1 * inv};
    *(float2*)&out[(size_t)node * DD + lane * 2] = res;
}

// ---------------- launch -----------------------------------------------------
extern "C" void kernel_launch(void* const* d_in, const int* in_sizes, int n_in,
                              void* d_out, int out_size, void* d_ws, size_t ws_size,
                              hipStream_t stream) {
    const float* ef  = (const float*)d_in[0];
    const float* nf  = (const float*)d_in[1];
    const int*   eix = (const int*)d_in[2];
    const float* W1  = (const float*)d_in[3];
    const float* b1  = (const float*)d_in[4];
    const float* W2  = (const float*)d_in[5];
    const float* b2  = (const float*)d_in[6];
    float* out = (float*)d_out;
    char* ws = (char*)d_ws;

    ushort_t* hpre  = (ushort_t*)(ws + 0);           // 25,600,000
    ushort_t* hh    = (ushort_t*)(ws + 25600000);    // 25,600,000
    ushort_t* e0    = (ushort_t*)(ws + 51200000);    // 163,840,000
    int*      cnt   = (int*)(ws + 215040000);        // 400,000
    u64*      stats = (u64*)(ws + 215440000);        // 64 B
    int*      slot  = (int*)(ws + 215440064);        // 25,600,000

    hipMemsetAsync(cnt, 0, 400064, stream);
    k1_gemm1<<<782, 256, 0, stream>>>(nf, W1, b1, hpre, stats, 782);
    k2b_gemmh<<<782, 256, 0, stream>>>(hpre, W2, stats, hh, 782);
    k7_fill<<<2500, 256, 0, stream>>>(eix, cnt, slot);
    k4_gemm2<<<2500, 256, 0, stream>>>(ef, hh, eix, W2, b2, e0, stats, 2500);
    k8_gather<<<25000, 256, 0, stream>>>(e0, slot, cnt, stats, out);
}

// Round 6
// 302.039 us; speedup vs baseline: 1.1119x; 1.0307x over previous
//
#include <hip/hip_runtime.h>
#include <hip/hip_bf16.h>
#include <math.h>

typedef __bf16 bf16;
typedef bf16 bf16x8 __attribute__((ext_vector_type(8)));
typedef float f32x4 __attribute__((ext_vector_type(4)));
typedef unsigned short ushort_t;
typedef unsigned long long u64;

#define N_NODES 100000
#define N_EDGES 640000
#define DD 128
#define MAXDEG 64
#define STAT_SCALE 1048576.0

__device__ __forceinline__ float gelu_fast(float x) {
    float z2 = x * (1.595769122f + 0.071354816f * x * x);
    return x * __builtin_amdgcn_rcpf(1.0f + __expf(-z2));
}

__device__ __forceinline__ ushort_t bf16_bits(float x) {
    bf16 h = (bf16)x;
    return __builtin_bit_cast(ushort_t, h);
}

__device__ __forceinline__ float bits_to_f(ushort_t u) {
    return __uint_as_float(((unsigned)u) << 16);
}

__device__ __forceinline__ long long to_fixed(double x) {
    return (long long)(x * STAT_SCALE + (x >= 0.0 ? 0.5 : -0.5));
}

__device__ __forceinline__ void stats_atomic(float lsum, float lsq, float* red,
                                             u64* dsum, u64* dsq) {
    int tid = threadIdx.x;
    red[tid] = lsum; __syncthreads();
    for (int s = 128; s > 0; s >>= 1) { if (tid < s) red[tid] += red[tid + s]; __syncthreads(); }
    float bs = red[0]; __syncthreads();
    red[tid] = lsq; __syncthreads();
    for (int s = 128; s > 0; s >>= 1) { if (tid < s) red[tid] += red[tid + s]; __syncthreads(); }
    if (tid == 0) {
        atomicAdd(dsum, (u64)to_fixed((double)bs));
        atomicAdd(dsq,  (u64)to_fixed((double)red[0]));
    }
}

__device__ __forceinline__ void stats_decode(const u64* stats, double cnt,
                                             float* mu, float* rs) {
    long long ss = (long long)stats[0], sq = (long long)stats[1];
    double mu_d = ((double)ss / STAT_SCALE) / cnt;
    double var  = ((double)sq / STAT_SCALE) / cnt - mu_d * mu_d;
    *mu = (float)mu_d;
    *rs = (float)(1.0 / sqrt(var + 1e-5));
}

#define PACK8(dstp, a, b) { \
    ushort_t o_[8] = {bf16_bits(a.x), bf16_bits(a.y), bf16_bits(a.z), bf16_bits(a.w), \
                      bf16_bits(b.x), bf16_bits(b.y), bf16_bits(b.z), bf16_bits(b.w)}; \
    *(uint4*)(dstp) = *(const uint4*)o_; }

// ---------------- K1: hpre = bf16(nf @ W1 + b1) + stats1 ---------------------
// Software-pipelined: next tile's fp32 panel prefetched into regs during MFMA.
#define K1_TILES 1563
__global__ __launch_bounds__(256) void k1_gemm1(
    const float* __restrict__ nf, const float* __restrict__ W1,
    const float* __restrict__ b1, ushort_t* __restrict__ hpre,
    u64* __restrict__ stats, int nblocks)
{
    __shared__ bf16 Ash[64 * 136];
    __shared__ float red[256];
    const int tid = threadIdx.x;
    const int lane = tid & 63;
    const int w = tid >> 6;
    const int l15 = lane & 15, l4 = lane >> 4;

    bf16x8 bfrag[4][2];
    #pragma unroll
    for (int s = 0; s < 4; ++s)
        #pragma unroll
        for (int t = 0; t < 2; ++t) {
            int n = w * 32 + t * 16 + l15;
            #pragma unroll
            for (int j = 0; j < 8; ++j)
                bfrag[s][t][j] = (bf16)W1[(s * 32 + l4 * 8 + j) * DD + n];
        }
    float4 bias4[2];
    bias4[0] = *(const float4*)&b1[w * 32 + l4 * 4];
    bias4[1] = *(const float4*)&b1[w * 32 + 16 + l4 * 4];

    float lsum = 0.f, lsq = 0.f;
    const int srow = tid >> 2;
    const int q = tid & 3;

    float4 efr[8];
    {   // prologue load
        int grow = min(blockIdx.x * 64 + srow, N_NODES - 1);
        const float4* p = (const float4*)&nf[(size_t)grow * DD + q * 32];
        #pragma unroll
        for (int u = 0; u < 8; ++u) efr[u] = p[u];
    }

    for (int tile = blockIdx.x; tile < K1_TILES; tile += nblocks) {
        const int rbase = tile * 64;
        __syncthreads();   // prev MFMA readers done
        #pragma unroll
        for (int u = 0; u < 4; ++u)
            PACK8(&Ash[srow * 136 + q * 32 + u * 8], efr[2 * u], efr[2 * u + 1]);
        __syncthreads();
        int nt = tile + nblocks;
        if (nt < K1_TILES) {   // prefetch next tile
            int grow = min(nt * 64 + srow, N_NODES - 1);
            const float4* p = (const float4*)&nf[(size_t)grow * DD + q * 32];
            #pragma unroll
            for (int u = 0; u < 8; ++u) efr[u] = p[u];
        }
        f32x4 acc[4][2];
        #pragma unroll
        for (int r = 0; r < 4; ++r)
            #pragma unroll
            for (int t = 0; t < 2; ++t)
                acc[r][t] = (f32x4){0.f, 0.f, 0.f, 0.f};
        #pragma unroll
        for (int s = 0; s < 4; ++s)
            #pragma unroll
            for (int r = 0; r < 4; ++r) {
                bf16x8 a = *(const bf16x8*)&Ash[(r * 16 + l15) * 136 + s * 32 + l4 * 8];
                acc[r][0] = __builtin_amdgcn_mfma_f32_16x16x32_bf16(bfrag[s][0], a, acc[r][0], 0, 0, 0);
                acc[r][1] = __builtin_amdgcn_mfma_f32_16x16x32_bf16(bfrag[s][1], a, acc[r][1], 0, 0, 0);
            }
        #pragma unroll
        for (int r = 0; r < 4; ++r) {
            int row = rbase + r * 16 + l15;
            if (row < N_NODES) {
                #pragma unroll
                for (int t = 0; t < 2; ++t) {
                    int col = w * 32 + t * 16 + l4 * 4;
                    ushort_t o[4];
                    #pragma unroll
                    for (int j = 0; j < 4; ++j) {
                        float v = acc[r][t][j] + bias4[t][j];
                        lsum += v; lsq += v * v;
                        o[j] = bf16_bits(v);
                    }
                    *(uint2*)&hpre[(size_t)row * DD + col] = *(const uint2*)o;
                }
            }
        }
    }
    stats_atomic(lsum, lsq, red, &stats[0], &stats[1]);
}

// ---------------- K2b: hh = bf16( gelu(LN(hpre)) @ W2_bot ) ------------------
__global__ __launch_bounds__(256) void k2b_gemmh(
    const ushort_t* __restrict__ hpre, const float* __restrict__ W2,
    const u64* __restrict__ stats, ushort_t* __restrict__ hh, int nblocks)
{
    __shared__ bf16 Ash[64 * 136];
    float mu, rs;
    stats_decode(stats, (double)N_NODES * DD, &mu, &rs);

    const int tid = threadIdx.x;
    const int lane = tid & 63;
    const int w = tid >> 6;
    const int l15 = lane & 15, l4 = lane >> 4;

    bf16x8 bfrag[4][2];
    #pragma unroll
    for (int s = 0; s < 4; ++s)
        #pragma unroll
        for (int t = 0; t < 2; ++t) {
            int n = w * 32 + t * 16 + l15;
            #pragma unroll
            for (int j = 0; j < 8; ++j)
                bfrag[s][t][j] = (bf16)W2[(DD + s * 32 + l4 * 8 + j) * DD + n];
        }

    const int srow = tid >> 2;
    const int q = tid & 3;

    uint4 hr[4];
    {
        int grow = min(blockIdx.x * 64 + srow, N_NODES - 1);
        const uint4* p = (const uint4*)&hpre[(size_t)grow * DD + q * 32];
        #pragma unroll
        for (int u = 0; u < 4; ++u) hr[u] = p[u];
    }

    for (int tile = blockIdx.x; tile < K1_TILES; tile += nblocks) {
        const int rbase = tile * 64;
        __syncthreads();
        #pragma unroll
        for (int u = 0; u < 4; ++u) {
            const ushort_t* in = (const ushort_t*)&hr[u];
            ushort_t o[8];
            #pragma unroll
            for (int j = 0; j < 8; ++j)
                o[j] = bf16_bits(gelu_fast((bits_to_f(in[j]) - mu) * rs));
            *(uint4*)&Ash[srow * 136 + q * 32 + u * 8] = *(const uint4*)o;
        }
        __syncthreads();
        int nt = tile + nblocks;
        if (nt < K1_TILES) {
            int grow = min(nt * 64 + srow, N_NODES - 1);
            const uint4* p = (const uint4*)&hpre[(size_t)grow * DD + q * 32];
            #pragma unroll
            for (int u = 0; u < 4; ++u) hr[u] = p[u];
        }
        f32x4 acc[4][2];
        #pragma unroll
        for (int r = 0; r < 4; ++r)
            #pragma unroll
            for (int t = 0; t < 2; ++t)
                acc[r][t] = (f32x4){0.f, 0.f, 0.f, 0.f};
        #pragma unroll
        for (int s = 0; s < 4; ++s)
            #pragma unroll
            for (int r = 0; r < 4; ++r) {
                bf16x8 a = *(const bf16x8*)&Ash[(r * 16 + l15) * 136 + s * 32 + l4 * 8];
                acc[r][0] = __builtin_amdgcn_mfma_f32_16x16x32_bf16(bfrag[s][0], a, acc[r][0], 0, 0, 0);
                acc[r][1] = __builtin_amdgcn_mfma_f32_16x16x32_bf16(bfrag[s][1], a, acc[r][1], 0, 0, 0);
            }
        #pragma unroll
        for (int r = 0; r < 4; ++r) {
            int row = rbase + r * 16 + l15;
            if (row < N_NODES) {
                #pragma unroll
                for (int t = 0; t < 2; ++t) {
                    int col = w * 32 + t * 16 + l4 * 4;
                    ushort_t o[4];
                    #pragma unroll
                    for (int j = 0; j < 4; ++j)
                        o[j] = bf16_bits(acc[r][t][j]);
                    *(uint2*)&hh[(size_t)row * DD + col] = *(const uint2*)o;
                }
            }
        }
    }
}

// ---------------- K4: e0 = bf16( ef @ W2_top + hh[src] + b2 ) + stats2 -------
// Pipelined streaming GEMM; hh gather issued at tile-top (latency hidden).
#define K4_TILES (N_EDGES / 64)
__global__ __launch_bounds__(256) void k4_gemm2(
    const float* __restrict__ ef, const ushort_t* __restrict__ hh,
    const int* __restrict__ eidx, const float* __restrict__ W2,
    const float* __restrict__ b2, ushort_t* __restrict__ e0,
    u64* __restrict__ stats, int nblocks)
{
    __shared__ bf16 Ash[64 * 136];
    __shared__ float red[256];
    const int tid = threadIdx.x;
    const int lane = tid & 63;
    const int w = tid >> 6;
    const int l15 = lane & 15, l4 = lane >> 4;

    bf16x8 bfrag[4][2];
    #pragma unroll
    for (int s = 0; s < 4; ++s)
        #pragma unroll
        for (int t = 0; t < 2; ++t) {
            int n = w * 32 + t * 16 + l15;
            #pragma unroll
            for (int j = 0; j < 8; ++j)
                bfrag[s][t][j] = (bf16)W2[(s * 32 + l4 * 8 + j) * DD + n];
        }
    float4 bias4[2];
    bias4[0] = *(const float4*)&b2[w * 32 + l4 * 4];
    bias4[1] = *(const float4*)&b2[w * 32 + 16 + l4 * 4];

    float lsum = 0.f, lsq = 0.f;
    const int srow = tid >> 2;
    const int q = tid & 3;

    float4 efr[8];
    {
        const float4* p = (const float4*)&ef[(size_t)(blockIdx.x * 64 + srow) * DD + q * 32];
        #pragma unroll
        for (int u = 0; u < 8; ++u) efr[u] = p[u];
    }

    for (int tile = blockIdx.x; tile < K4_TILES; tile += nblocks) {
        const int ebase = tile * 64;
        // gather prefetch: independent of LDS, consumed in epilogue
        int srcv[4];
        #pragma unroll
        for (int r = 0; r < 4; ++r)
            srcv[r] = eidx[(size_t)(ebase + r * 16 + l15) * 2];
        uint2 hv[4][2];
        #pragma unroll
        for (int r = 0; r < 4; ++r)
            #pragma unroll
            for (int t = 0; t < 2; ++t)
                hv[r][t] = *(const uint2*)&hh[(size_t)srcv[r] * DD + w * 32 + t * 16 + l4 * 4];
        __syncthreads();
        #pragma unroll
        for (int u = 0; u < 4; ++u)
            PACK8(&Ash[srow * 136 + q * 32 + u * 8], efr[2 * u], efr[2 * u + 1]);
        __syncthreads();
        int nt = tile + nblocks;
        if (nt < K4_TILES) {
            const float4* p = (const float4*)&ef[(size_t)(nt * 64 + srow) * DD + q * 32];
            #pragma unroll
            for (int u = 0; u < 8; ++u) efr[u] = p[u];
        }
        f32x4 acc[4][2];
        #pragma unroll
        for (int r = 0; r < 4; ++r)
            #pragma unroll
            for (int t = 0; t < 2; ++t)
                acc[r][t] = (f32x4){0.f, 0.f, 0.f, 0.f};
        #pragma unroll
        for (int s = 0; s < 4; ++s)
            #pragma unroll
            for (int r = 0; r < 4; ++r) {
                bf16x8 a = *(const bf16x8*)&Ash[(r * 16 + l15) * 136 + s * 32 + l4 * 8];
                acc[r][0] = __builtin_amdgcn_mfma_f32_16x16x32_bf16(bfrag[s][0], a, acc[r][0], 0, 0, 0);
                acc[r][1] = __builtin_amdgcn_mfma_f32_16x16x32_bf16(bfrag[s][1], a, acc[r][1], 0, 0, 0);
            }
        #pragma unroll
        for (int r = 0; r < 4; ++r) {
            int row = ebase + r * 16 + l15;
            #pragma unroll
            for (int t = 0; t < 2; ++t) {
                int col = w * 32 + t * 16 + l4 * 4;
                float hadd[4] = {bits_to_f((ushort_t)(hv[r][t].x & 0xffff)),
                                 bits_to_f((ushort_t)(hv[r][t].x >> 16)),
                                 bits_to_f((ushort_t)(hv[r][t].y & 0xffff)),
                                 bits_to_f((ushort_t)(hv[r][t].y >> 16))};
                ushort_t o[4];
                #pragma unroll
                for (int j = 0; j < 4; ++j) {
                    float v = acc[r][t][j] + bias4[t][j] + hadd[j];
                    lsum += v; lsq += v * v;
                    o[j] = bf16_bits(v);
                }
                *(uint2*)&e0[(size_t)row * DD + col] = *(const uint2*)o;
            }
        }
    }
    stats_atomic(lsum, lsq, red, &stats[2], &stats[3]);
}

// ---------------- K7: bucket edges by dst ------------------------------------
__global__ __launch_bounds__(256) void k7_fill(
    const int* __restrict__ eidx, int* __restrict__ cnt, int* __restrict__ slot)
{
    int e = blockIdx.x * 256 + threadIdx.x;
    if (e >= N_EDGES) return;
    int dst = eidx[(size_t)e * 2 + 1];
    int pos = atomicAdd(&cnt[dst], 1);
    if (pos < MAXDEG) slot[dst * MAXDEG + pos] = e;
}

// ---------------- K8: per-node gather + norm + fast-gelu + mean --------------
__global__ __launch_bounds__(256) void k8_gather(
    const ushort_t* __restrict__ e0v, const int* __restrict__ slot,
    const int* __restrict__ cnt, const u64* __restrict__ stats,
    float* __restrict__ out)
{
    float mu, rs;
    stats_decode(stats + 2, (double)N_EDGES * DD, &mu, &rs);
    int node = (int)((blockIdx.x * 256 + threadIdx.x) >> 6);
    int lane = threadIdx.x & 63;
    if (node >= N_NODES) return;
    int c = cnt[node];
    int m = min(c, MAXDEG);
    int myslot = (lane < m) ? slot[node * MAXDEG + lane] : 0;
    float a0 = 0.f, a1 = 0.f;
    const size_t off = (size_t)(lane * 2);
    int j = 0;
    for (; j + 4 <= m; j += 4) {
        int ea = __shfl(myslot, j);
        int eb = __shfl(myslot, j + 1);
        int ec = __shfl(myslot, j + 2);
        int ed = __shfl(myslot, j + 3);
        unsigned ua = *(const unsigned*)&e0v[(size_t)ea * DD + off];
        unsigned ub = *(const unsigned*)&e0v[(size_t)eb * DD + off];
        unsigned uc = *(const unsigned*)&e0v[(size_t)ec * DD + off];
        unsigned ud = *(const unsigned*)&e0v[(size_t)ed * DD + off];
        a0 += gelu_fast((__uint_as_float(ua << 16) - mu) * rs);
        a1 += gelu_fast((__uint_as_float(ua & 0xffff0000u) - mu) * rs);
        a0 += gelu_fast((__uint_as_float(ub << 16) - mu) * rs);
        a1 += gelu_fast((__uint_as_float(ub & 0xffff0000u) - mu) * rs);
        a0 += gelu_fast((__uint_as_float(uc << 16) - mu) * rs);
        a1 += gelu_fast((__uint_as_float(uc & 0xffff0000u) - mu) * rs);
        a0 += gelu_fast((__uint_as_float(ud << 16) - mu) * rs);
        a1 += gelu_fast((__uint_as_float(ud & 0xffff0000u) - mu) * rs);
    }
    for (; j < m; ++j) {
        int ea = __shfl(myslot, j);
        unsigned ua = *(const unsigned*)&e0v[(size_t)ea * DD + off];
        a0 += gelu_fast((__uint_as_float(ua << 16) - mu) * rs);
        a1 += gelu_fast((__uint_as_float(ua & 0xffff0000u) - mu) * rs);
    }
    float inv = c > 0 ? 1.0f / (float)c : 0.f;
    float2 res = {a0 * inv, a1 * inv};
    *(float2*)&out[(size_t)node * DD + lane * 2] = res;
}

// ---------------- launch -----------------------------------------------------
extern "C" void kernel_launch(void* const* d_in, const int* in_sizes, int n_in,
                              void* d_out, int out_size, void* d_ws, size_t ws_size,
                              hipStream_t stream) {
    const float* ef  = (const float*)d_in[0];
    const float* nf  = (const float*)d_in[1];
    const int*   eix = (const int*)d_in[2];
    const float* W1  = (const float*)d_in[3];
    const float* b1  = (const float*)d_in[4];
    const float* W2  = (const float*)d_in[5];
    const float* b2  = (const float*)d_in[6];
    float* out = (float*)d_out;
    char* ws = (char*)d_ws;

    ushort_t* hpre  = (ushort_t*)(ws + 0);           // 25,600,000
    ushort_t* hh    = (ushort_t*)(ws + 25600000);    // 25,600,000
    ushort_t* e0    = (ushort_t*)(ws + 51200000);    // 163,840,000
    int*      cnt   = (int*)(ws + 215040000);        // 400,000
    u64*      stats = (u64*)(ws + 215440000);        // 64 B
    int*      slot  = (int*)(ws + 215440064);        // 25,600,000

    hipMemsetAsync(cnt, 0, 400064, stream);
    k1_gemm1<<<521, 256, 0, stream>>>(nf, W1, b1, hpre, stats, 521);
    k2b_gemmh<<<521, 256, 0, stream>>>(hpre, W2, stats, hh, 521);
    k7_fill<<<2500, 256, 0, stream>>>(eix, cnt, slot);
    k4_gemm2<<<1250, 256, 0, stream>>>(ef, hh, eix, W2, b2, e0, stats, 1250);
    k8_gather<<<25000, 256, 0, stream>>>(e0, slot, cnt, stats, out);
}